// Round 13
// baseline (84.515 us; speedup 1.0000x reference)
//
#include <hip/hip_runtime.h>

// Problem constants
#define CIN   16
#define COUT  32
#define BATCH 2
#define DSP   32
#define HSP   128
#define WSP   128
#define NVOX  (BATCH*DSP*HSP*WSP)   // 1,048,576 voxels (unpadded, dedup map)

// padded dense grid, cin-QUARTER-plane layout: [b][q][zp][yp][xp] x 8B (4 bf16)
#define DP (DSP+2)     // 34
#define HP (HSP+2)     // 130
#define WP (WSP+2)     // 130
#define NVOXP (BATCH*DP*HP*WP)      // 1,149,200
#define NDCH2 (BATCH*4*DP*HP*(WP/2))  // 16B chunks of dense2 = 2,298,400

// conv tile: 4(z) x 8(y) x 32(x); halo patch 6 x 10 x 34
#define TZ 4
#define TY 8
#define TX 32
#define PZ 6
#define PYY 10
#define PXX 34
#define PROW (PYY*PXX)      // 340
#define PVOX (PZ*PROW)      // 2040 voxels
#define QCH   (PVOX/2)      // 16B chunks per quarter region (1020)
#define QUSH  (PVOX*4)      // ushorts per quarter region (8160)
#define NCHUNK (4*QCH)      // 4080 chunks total
#define NCHPAD 4096         // 8 waves * 8 issues * 64 lanes
#define NWREP ((27*2*64*4 + 255)/256)   // 54 repack blocks (13824 bf16)

typedef __bf16 bf16x4 __attribute__((ext_vector_type(4)));
typedef short  s16x4  __attribute__((ext_vector_type(4)));
typedef float  f32x4  __attribute__((ext_vector_type(4)));

// Device-only MFMA macro; host pass gets an inert stub (device code never runs on host).
#if defined(__HIP_DEVICE_COMPILE__)
  #if __has_builtin(__builtin_amdgcn_mfma_f32_16x16x16bf16_1k)
    #define MFMA16(A,B,C) __builtin_amdgcn_mfma_f32_16x16x16bf16_1k((A),(B),(C),0,0,0)
  #else
    #define MFMA16(A,B,C) __builtin_amdgcn_mfma_f32_16x16x16_bf16( \
        __builtin_bit_cast(bf16x4,(A)), __builtin_bit_cast(bf16x4,(B)), (C),0,0,0)
  #endif
#else
  #define MFMA16(A,B,C) (C)
#endif

// width-16 global->LDS DMA: uniform LDS base, per-lane global src
__device__ __forceinline__ void load_lds16(const void* g, void* l) {
    __builtin_amdgcn_global_load_lds(
        (const __attribute__((address_space(1))) unsigned*)g,
        (__attribute__((address_space(3))) unsigned*)l, 16, 0, 0);
}

// ---- fused: dedup (atomicMax last-write-wins) + K16 weight repack ----
// wpack idx = ((tap*2 + h)*64 + lane)*4 + j
// B-frag: cout = h*16 + (lane&15), cin = (lane>>4)*4 + j
__global__ void k_prep(const int4* __restrict__ coords, int n, int nbDedup,
                       int* __restrict__ map,
                       const float* __restrict__ w, __bf16* __restrict__ wpack) {
    int bb = blockIdx.x;
    if (bb < nbDedup) {
        int p = bb * 256 + threadIdx.x;
        if (p >= n) return;
        int4 c = coords[p];
        int vox = ((c.x*DSP + c.y)*HSP + c.z)*WSP + c.w;
        atomicMax(&map[vox], p);
    } else {
        int i = (bb - nbDedup) * 256 + threadIdx.x;   // 13824 total
        if (i >= 27*2*64*4) return;
        int j = i & 3, l = (i>>2) & 63, h = (i>>8) & 1, tap = i >> 9;
        int co = h*16 + (l & 15);
        int ci = (l>>4)*4 + j;
        wpack[i] = (__bf16)w[(co*CIN + ci)*27 + tap];
    }
}

// ---- dense fill, quarter-plane layout; one thread per 16B chunk (2 voxels) ----
__global__ void k_fill(const int* __restrict__ map, const float* __restrict__ feat,
                       __bf16* __restrict__ dense2) {
    int c = blockIdx.x * 256 + threadIdx.x;
    if (c >= NDCH2) return;
    int px2 = c % 65;  int r1 = c / 65;
    int yp  = r1 % HP; int r2 = r1 / HP;
    int zp  = r2 % DP; int r3 = r2 / DP;
    int q   = r3 & 3;  int b  = r3 >> 2;
    ushort out8[8] = {0,0,0,0,0,0,0,0};
    if ((unsigned)(zp-1) < DSP && (unsigned)(yp-1) < HSP) {
        #pragma unroll
        for (int s = 0; s < 2; ++s) {
            int gx = 2*px2 + s - 1;
            if ((unsigned)gx < WSP) {
                int vox = ((b*DSP + (zp-1))*HSP + (yp-1))*WSP + gx;
                int p = map[vox];
                if (p >= 0) {
                    float4 f = *(const float4*)(feat + (size_t)p*CIN + q*4);
                    bf16x4 v = { (__bf16)f.x, (__bf16)f.y, (__bf16)f.z, (__bf16)f.w };
                    *(bf16x4*)&out8[s*4] = v;
                }
            }
        }
    }
    size_t idx = ((((size_t)(b*4 + q)*DP + zp)*HP + yp)*WP + 2*px2)*4;
    *(uint4*)(dense2 + idx) = *(uint4*)out8;
}

// issue exactly 8 DMA per wave for one tile's patch (uniform vmcnt accounting)
__device__ __forceinline__ void stage_tile(const __bf16* __restrict__ gb,
                                           ushort* lbase, int wave, int lane) {
    #pragma unroll
    for (int it = 0; it < 8; ++it) {
        int j0 = wave*64 + it*512;                    // wave-uniform LDS chunk base
        int j  = j0 + lane;
        int jj = j < NCHUNK ? j : NCHUNK-1;           // clamp pad lanes (dup load)
        int q  = jj / QCH;
        int c2 = jj - q*QCH;
        int v  = c2*2;
        int pz = v / PROW;
        int rem = v - pz*PROW;
        int py = rem / PXX;
        int px = rem - py*PXX;
        // gb points at (b, q=0, z0, y0, x0); quarter stride = DP*HP*WP voxels
        load_lds16(gb + ((size_t)q*DP*HP*WP + (size_t)pz*HP*WP + (size_t)py*WP + px)*4,
                   (void*)(lbase + (size_t)j0*8));
    }
}

// ---- persistent pipelined conv, K16 MFMA with z-reuse: 1 block/CU, 4 tiles ----
// vmcnt queue at iter-t wait: [stage(t):8][wb(t-1):16][stage(t+1):8]
//   t=0: vmcnt(8) | t=1,2: vmcnt(24) | t=3: vmcnt(16)
__global__ __launch_bounds__(512, 2) void k_conv(
    const __bf16* __restrict__ dense2, const __bf16* __restrict__ wpack,
    const float* __restrict__ bias, float* __restrict__ out)
{
    __shared__ __align__(16) ushort patch[2][NCHPAD*8];   // 2 x 64 KiB

    // 256 blocks <-> (b, tz, ty); XCD-aware bijective swizzle (256 % 8 == 0)
    int bid = blockIdx.x;
    int bs  = (bid & 7) * 32 + (bid >> 3);
    int tyi = bs & 15, tzi = (bs >> 4) & 7, b = bs >> 7;
    int z0 = tzi*TZ, y0 = tyi*TY;

    int tid  = threadIdx.x;
    int lane = tid & 63, wave = tid >> 6;
    int lx16 = lane & 15;
    int lq   = lane >> 4;              // cin quarter

    float bv0 = bias[lx16], bv1 = bias[16 + lx16];

    // preload ALL K16 weight fragments: 27 taps x 2 halves x 8B = 108 VGPR
    s16x4 wf[27][2];
    #pragma unroll
    for (int tap = 0; tap < 27; ++tap)
        #pragma unroll
        for (int h = 0; h < 2; ++h)
            wf[tap][h] = *(const s16x4*)(wpack + (size_t)((tap*2 + h)*64 + lane)*4);

    // block's global base at (b, q=0, z0, y0, x=0) in 4-elem units
    const __bf16* grow = dense2 + (((size_t)(b*4)*DP + z0)*HP + y0)*(size_t)WP*4;

    // prologue: stage tile 0
    stage_tile(grow, patch[0], wave, lane);

    #pragma unroll 1
    for (int t = 0; t < 4; ++t) {
        if (t < 3) stage_tile(grow + (size_t)(t+1)*TX*4, patch[(t+1)&1], wave, lane);
        if (t == 0)      asm volatile("s_waitcnt vmcnt(8)\ns_barrier"  ::: "memory");
        else if (t < 3)  asm volatile("s_waitcnt vmcnt(24)\ns_barrier" ::: "memory");
        else             asm volatile("s_waitcnt vmcnt(16)\ns_barrier" ::: "memory");
        __builtin_amdgcn_sched_barrier(0);

        // ---- compute tile t: wave = y row; acc[z][xg][half] ----
        f32x4 acc[4][2][2];
        #pragma unroll
        for (int z = 0; z < 4; ++z)
            #pragma unroll
            for (int xg = 0; xg < 2; ++xg) {
                acc[z][xg][0] = (f32x4){0.f,0.f,0.f,0.f};
                acc[z][xg][1] = (f32x4){0.f,0.f,0.f,0.f};
            }
        const ushort* pbase = patch[t&1] + lq*QUSH;
        #pragma unroll
        for (int kh = 0; kh < 3; ++kh)
        #pragma unroll
        for (int kw = 0; kw < 3; ++kw)
        #pragma unroll
        for (int xg = 0; xg < 2; ++xg) {
            int vbase = (wave + kh)*PXX + xg*16 + kw + lx16;
            s16x4 r[6];
            #pragma unroll
            for (int pz = 0; pz < 6; ++pz)
                r[pz] = *(const s16x4*)(pbase + (size_t)(pz*PROW + vbase)*4);
            #pragma unroll
            for (int z = 0; z < 4; ++z)
                #pragma unroll
                for (int kd = 0; kd < 3; ++kd) {
                    int tap = (kd*3 + kh)*3 + kw;
                    acc[z][xg][0] = MFMA16(r[z+kd], wf[tap][0], acc[z][xg][0]);
                    acc[z][xg][1] = MFMA16(r[z+kd], wf[tap][1], acc[z][xg][1]);
                }
        }

        // all waves done reading patch[t&1] -> stage(t+2) may overwrite next iter
        asm volatile("s_barrier" ::: "memory");
        __builtin_amdgcn_sched_barrier(0);

        // ---- writeback: D col = cout-in-half, row = (lane>>4)*4+reg = x ----
        #pragma unroll
        for (int z = 0; z < 4; ++z)
        #pragma unroll
        for (int xg = 0; xg < 2; ++xg) {
            int gz = z0 + z, gy = y0 + wave;
            int gx = t*TX + xg*16 + (lq << 2);
            f32x4 o0, o1;
            o0[0] = fmaxf(acc[z][xg][0][0]+bv0, 0.f); o0[1] = fmaxf(acc[z][xg][0][1]+bv0, 0.f);
            o0[2] = fmaxf(acc[z][xg][0][2]+bv0, 0.f); o0[3] = fmaxf(acc[z][xg][0][3]+bv0, 0.f);
            o1[0] = fmaxf(acc[z][xg][1][0]+bv1, 0.f); o1[1] = fmaxf(acc[z][xg][1][1]+bv1, 0.f);
            o1[2] = fmaxf(acc[z][xg][1][2]+bv1, 0.f); o1[3] = fmaxf(acc[z][xg][1][3]+bv1, 0.f);
            size_t base0 = ((((size_t)b*COUT + lx16)*DSP + gz)*HSP + gy)*WSP + gx;
            size_t base1 = base0 + (size_t)16*DSP*HSP*WSP;
            *(f32x4*)(out + base0) = o0;
            *(f32x4*)(out + base1) = o1;
        }
    }
}

extern "C" void kernel_launch(void* const* d_in, const int* in_sizes, int n_in,
                              void* d_out, int out_size, void* d_ws, size_t ws_size,
                              hipStream_t stream) {
    const float* feat   = (const float*)d_in[0];
    const int4*  coords = (const int4*)d_in[1];
    const float* weight = (const float*)d_in[2];
    const float* bias   = (const float*)d_in[3];
    float* out = (float*)d_out;
    int n = in_sizes[0] / CIN;

    // workspace: map 4MB | dense2 (quarter-plane, 36.8MB) | wpack 27.6KB
    int*    map    = (int*)d_ws;
    __bf16* dense2 = (__bf16*)(map + NVOX);
    __bf16* wpack  = dense2 + (size_t)NVOXP*CIN;

    (void)hipMemsetAsync(map, 0xFF, (size_t)NVOX*sizeof(int), stream);

    int nb = (n + 255) / 256;
    k_prep<<<nb + NWREP, 256, 0, stream>>>(coords, n, nb, map, weight, wpack);
    k_fill<<<(NDCH2 + 255)/256, 256, 0, stream>>>(map, feat, dense2);
    k_conv<<<256, 512, 0, stream>>>(dense2, wpack, bias, out);
}

// Round 14
// 68.104 us; speedup vs baseline: 1.2410x; 1.2410x over previous
//
#include <hip/hip_runtime.h>

// Problem constants
#define CIN   16
#define COUT  32
#define BATCH 2
#define DSP   32
#define HSP   128
#define WSP   128
#define NVOX  (BATCH*DSP*HSP*WSP)   // 1,048,576 voxels (unpadded, dedup map)

// padded dense grid (1-voxel zero halo), voxel-major: [b][zp][yp][xp] x 16 bf16
#define DP (DSP+2)     // 34
#define HP (HSP+2)     // 130
#define WP (WSP+2)     // 130
#define NVOXP (BATCH*DP*HP*WP)      // 1,149,200
#define NDCH  (NVOXP*2)             // 16B chunks of dense

// conv tile: 2(z) x 8(y) x 16(x), walked 8x in x (persistent); patch 4 x 10 x 18
#define TZ 2
#define TY 8
#define TX 16
#define NTW 8                // x-tiles per block
#define PZ 4
#define PYY 10
#define PXX 18
#define PROW (PYY*PXX)       // 180
#define PVOX (PZ*PROW)       // 720 voxels
#define NCHUNK (2*PVOX)      // 1440 16B chunks per buffer ([half][voxel])
#define SLICE  (NCHUNK/8)    // 180 chunks per wave
#define NPAIR 14             // 27 taps -> 14 K=32 pairs (last padded with zero wts)
#define NWEL  (NPAIR*2*64*8) // 14336 bf16 weight elements
#define WCH   (NWEL/8)       // 1792 16B chunks
#define WSLICE (WCH/8)       // 224 chunks per wave
#define NWREP ((NWEL + 255)/256)   // 56 repack blocks
#define NBLK  512            // (b:2, tz:16, ty:16)

typedef __bf16 bf16x8 __attribute__((ext_vector_type(8)));
typedef float  f32x4  __attribute__((ext_vector_type(4)));

// width-16 global->LDS DMA: uniform LDS base, per-lane global src
__device__ __forceinline__ void load_lds16(const void* g, void* l) {
    __builtin_amdgcn_global_load_lds(
        (const __attribute__((address_space(1))) unsigned*)g,
        (__attribute__((address_space(3))) unsigned*)l, 16, 0, 0);
}

// ---- fused: dedup (atomicMax last-write-wins) + K32 weight repack ----
// wpack idx = ((pair*2 + h)*64 + lane)*8 + j
// tap = 2*pair + ((lane>>4)>>1), ci = ((lane>>4)&1)*8 + j, cout = h*16 + (lane&15)
__global__ void k_prep(const int4* __restrict__ coords, int n, int nbDedup,
                       int* __restrict__ map,
                       const float* __restrict__ w, __bf16* __restrict__ wpack) {
    int bb = blockIdx.x;
    if (bb < nbDedup) {
        int p = bb * 256 + threadIdx.x;
        if (p >= n) return;
        int4 c = coords[p];
        int vox = ((c.x*DSP + c.y)*HSP + c.z)*WSP + c.w;
        atomicMax(&map[vox], p);
    } else {
        int i = (bb - nbDedup) * 256 + threadIdx.x;   // 14336 total
        if (i >= NWEL) return;
        int j = i & 7, l = (i>>3) & 63, h = (i>>9) & 1, p = i >> 10;
        int tap = 2*p + ((l>>4)>>1);
        int co  = h*16 + (l & 15);
        int ci  = ((l>>4)&1)*8 + j;
        float v = (tap < 27) ? w[(co*CIN + ci)*27 + tap] : 0.0f;
        wpack[i] = (__bf16)v;
    }
}

// ---- dense fill: one thread per 16B chunk; zeros or gathered bf16 features ----
__global__ void k_fill(const int* __restrict__ map, const float* __restrict__ feat,
                       __bf16* __restrict__ dense) {
    int c = blockIdx.x * 256 + threadIdx.x;
    if (c >= NDCH) return;
    int v = c >> 1, h = c & 1;
    int bb = v / (DP*HP*WP);
    int r  = v - bb*(DP*HP*WP);
    int zp = r / (HP*WP);  r -= zp*(HP*WP);
    int yp = r / WP;
    int xp = r - yp*WP;
    bf16x8 val = { (__bf16)0.f,(__bf16)0.f,(__bf16)0.f,(__bf16)0.f,
                   (__bf16)0.f,(__bf16)0.f,(__bf16)0.f,(__bf16)0.f };
    if ((unsigned)(zp-1) < DSP && (unsigned)(yp-1) < HSP && (unsigned)(xp-1) < WSP) {
        int vox = ((bb*DSP + (zp-1))*HSP + (yp-1))*WSP + (xp-1);
        int p = map[vox];
        if (p >= 0) {
            const float4* fp = (const float4*)(feat + (size_t)p*CIN) + h*2;
            float4 f0 = fp[0], f1 = fp[1];
            val = bf16x8{ (__bf16)f0.x,(__bf16)f0.y,(__bf16)f0.z,(__bf16)f0.w,
                          (__bf16)f1.x,(__bf16)f1.y,(__bf16)f1.z,(__bf16)f1.w };
        }
    }
    *(bf16x8*)(dense + (size_t)v*CIN + h*8) = val;
}

// stage one tile's patch: exactly 3 DMA instructions per wave (uniform vmcnt),
// exec-masked tail (every issue has >=1 active lane in every wave)
__device__ __forceinline__ void stage_tile(const __bf16* __restrict__ gb,
                                           ushort* lbase, int wave, int lane) {
    #pragma unroll
    for (int it = 0; it < 3; ++it) {
        int rel = it*64 + lane;
        if (rel < SLICE) {
            int j = wave*SLICE + rel;
            int h = (j >= PVOX) ? 1 : 0;
            int v = j - h*PVOX;
            int pz = v / PROW;
            int rm = v - pz*PROW;
            int py = rm / PXX;
            int px = rm - py*PXX;
            load_lds16(gb + ((size_t)(pz*HP*WP + py*WP + px))*CIN + h*8,
                       (void*)(lbase + (size_t)(wave*SLICE + it*64)*8));
        }
    }
}

// ---- persistent pipelined conv (MFMA): 2 blocks/CU, 8 x-tiles, 2-deep dbuf ----
// per-wave vmcnt FIFO at iter-t wait: [stage(t):3][wb(t-1):4][stage(t+1):3]
//   t=0: vmcnt(3) | 0<t<7: vmcnt(7) | t=7: vmcnt(4)
__global__ __launch_bounds__(512, 4) void k_conv(
    const __bf16* __restrict__ dense, const __bf16* __restrict__ wpack,
    const float* __restrict__ bias, float* __restrict__ out)
{
    __shared__ __align__(16) ushort patch[2][NCHUNK*8];  // 2 x 23040 B
    __shared__ __align__(16) ushort wlds[WCH*8];         // 28672 B

    // 512 blocks <-> (b, tz, ty); XCD-aware bijective swizzle (512 % 8 == 0)
    int bid = blockIdx.x;
    int bs  = (bid & 7) * (NBLK/8) + (bid >> 3);
    int tyi = bs & 15, tzi = (bs >> 4) & 15, b = bs >> 8;
    int z0 = tzi*TZ, y0 = tyi*TY;

    int tid  = threadIdx.x;
    int lane = tid & 63, wave = tid >> 6;
    int lx16  = lane & 15;
    int lhalf = (lane >> 4) & 1;
    int ltp   = (lane >> 4) >> 1;
    int lq    = lane >> 4;
    int zw    = wave >> 2;           // output z (0..1)
    int ysub  = (wave & 3) * 2;      // output y base (0,2,4,6)

    // per-lane patch voxel offsets per tap-pair
    int voff[NPAIR];
    #pragma unroll
    for (int p = 0; p < NPAIR; ++p) {
        int tap = 2*p + ltp; if (tap > 26) tap = 26;   // A in-bounds; B zero there
        int kd = tap/9, kh = (tap/3)%3, kw = tap%3;
        voff[p] = (kd*PYY + kh)*PXX + kw;
    }
    float bv0 = bias[lx16], bv1 = bias[16 + lx16];

    // prologue: stage weights (4 DMA/wave) + tile 0 (3 DMA/wave), drain all
    #pragma unroll
    for (int it = 0; it < 4; ++it) {
        int rel = it*64 + lane;
        if (rel < WSLICE) {
            int c0 = wave*WSLICE + it*64;
            load_lds16(wpack + (size_t)(c0 + lane)*8, (void*)(wlds + (size_t)c0*8));
        }
    }
    const __bf16* gbase = dense + ((((size_t)b*DP + z0)*HP + y0)*WP)*CIN;
    stage_tile(gbase, patch[0], wave, lane);
    asm volatile("s_waitcnt vmcnt(0)\ns_barrier" ::: "memory");
    __builtin_amdgcn_sched_barrier(0);

    int bufc = 0;
    #pragma unroll 1
    for (int t = 0; t < NTW; ++t) {
        if (t < NTW-1)
            stage_tile(gbase + (size_t)(t+1)*TX*CIN, patch[bufc^1], wave, lane);
        if (t == 0)          asm volatile("s_waitcnt vmcnt(3)\ns_barrier" ::: "memory");
        else if (t < NTW-1)  asm volatile("s_waitcnt vmcnt(7)\ns_barrier" ::: "memory");
        else                 asm volatile("s_waitcnt vmcnt(4)\ns_barrier" ::: "memory");
        __builtin_amdgcn_sched_barrier(0);

        // ---- compute tile t from patch[bufc]; weights from LDS per pair ----
        f32x4 acc[2][2];
        acc[0][0] = (f32x4){0.f,0.f,0.f,0.f}; acc[0][1] = (f32x4){0.f,0.f,0.f,0.f};
        acc[1][0] = (f32x4){0.f,0.f,0.f,0.f}; acc[1][1] = (f32x4){0.f,0.f,0.f,0.f};
        const ushort* pb = patch[bufc] +
            ((size_t)lhalf*PVOX + (zw*PYY + ysub)*PXX + lx16)*8;
        __builtin_amdgcn_s_setprio(1);
        #pragma unroll
        for (int p = 0; p < NPAIR; ++p) {
            bf16x8 w0 = *(const bf16x8*)(wlds + (size_t)((p*2+0)*64 + lane)*8);
            bf16x8 w1 = *(const bf16x8*)(wlds + (size_t)((p*2+1)*64 + lane)*8);
            const ushort* pa = pb + (size_t)voff[p]*8;
            #pragma unroll
            for (int gi = 0; gi < 2; ++gi) {
                bf16x8 a = *(const bf16x8*)(pa + gi*(PXX*8));
                acc[gi][0] = __builtin_amdgcn_mfma_f32_16x16x32_bf16(a, w0, acc[gi][0], 0,0,0);
                acc[gi][1] = __builtin_amdgcn_mfma_f32_16x16x32_bf16(a, w1, acc[gi][1], 0,0,0);
            }
        }
        __builtin_amdgcn_s_setprio(0);

        // all waves done reading patch[bufc] -> stage(t+2) may overwrite next iter
        asm volatile("s_barrier" ::: "memory");
        __builtin_amdgcn_sched_barrier(0);

        // ---- writeback: D col = cout-in-half, row = (lane>>4)*4+reg = x ----
        #pragma unroll
        for (int gi = 0; gi < 2; ++gi) {
            int gz = z0 + zw, gy = y0 + ysub + gi;
            int gx = t*TX + (lq << 2);
            f32x4 o0, o1;
            o0[0] = fmaxf(acc[gi][0][0]+bv0, 0.f); o0[1] = fmaxf(acc[gi][0][1]+bv0, 0.f);
            o0[2] = fmaxf(acc[gi][0][2]+bv0, 0.f); o0[3] = fmaxf(acc[gi][0][3]+bv0, 0.f);
            o1[0] = fmaxf(acc[gi][1][0]+bv1, 0.f); o1[1] = fmaxf(acc[gi][1][1]+bv1, 0.f);
            o1[2] = fmaxf(acc[gi][1][2]+bv1, 0.f); o1[3] = fmaxf(acc[gi][1][3]+bv1, 0.f);
            size_t base0 = ((((size_t)b*COUT + lx16)*DSP + gz)*HSP + gy)*WSP + gx;
            size_t base1 = base0 + (size_t)16*DSP*HSP*WSP;
            *(f32x4*)(out + base0) = o0;
            *(f32x4*)(out + base1) = o1;
        }
        bufc ^= 1;
    }
}

extern "C" void kernel_launch(void* const* d_in, const int* in_sizes, int n_in,
                              void* d_out, int out_size, void* d_ws, size_t ws_size,
                              hipStream_t stream) {
    const float* feat   = (const float*)d_in[0];
    const int4*  coords = (const int4*)d_in[1];
    const float* weight = (const float*)d_in[2];
    const float* bias   = (const float*)d_in[3];
    float* out = (float*)d_out;
    int n = in_sizes[0] / CIN;

    // workspace: map 4MB | dense(padded) 36.8MB | wpack 28.7KB
    int*    map   = (int*)d_ws;
    __bf16* dense = (__bf16*)(map + NVOX);
    __bf16* wpack = dense + (size_t)NVOXP*CIN;

    (void)hipMemsetAsync(map, 0xFF, (size_t)NVOX*sizeof(int), stream);

    int nb = (n + 255) / 256;
    k_prep<<<nb + NWREP, 256, 0, stream>>>(coords, n, nb, map, weight, wpack);
    k_fill<<<(NDCH + 255)/256, 256, 0, stream>>>(map, feat, dense);
    k_conv<<<NBLK, 512, 0, stream>>>(dense, wpack, bias, out);
}